// Round 1
// baseline (442.748 us; speedup 1.0000x reference)
//
#include <hip/hip_runtime.h>
#include <stdint.h>

// ---------------------------------------------------------------------------
// Types
// ---------------------------------------------------------------------------
typedef __attribute__((ext_vector_type(8))) short bf16x8;   // 8 bf16 (4 VGPRs)
typedef __attribute__((ext_vector_type(4))) float f32x4;    // MFMA accumulator

__device__ __forceinline__ unsigned short f2b(float f) {
  union { float f; uint32_t u; } v; v.f = f;
  uint32_t u = v.u;
  return (unsigned short)((u + 0x7FFFu + ((u >> 16) & 1u)) >> 16);  // RNE
}

// async global->LDS, 16B per lane. lds_uniform = wave-uniform base; HW writes
// lane i at base + i*16. Global src is per-lane.
__device__ __forceinline__ void gll16(const unsigned short* gsrc, unsigned short* lds_uniform) {
  __builtin_amdgcn_global_load_lds(
      (const __attribute__((address_space(1))) uint32_t*)gsrc,
      (__attribute__((address_space(3))) uint32_t*)lds_uniform,
      16, 0, 0);
}

#define MFMA(a, b, c) __builtin_amdgcn_mfma_f32_16x16x32_bf16((a), (b), (c), 0, 0, 0)

// ---------------------------------------------------------------------------
// f32 -> bf16 cast (vectorized)
// ---------------------------------------------------------------------------
__global__ void cast_f32_bf16(const float* __restrict__ src, unsigned short* __restrict__ dst, int n) {
  int i = (blockIdx.x * blockDim.x + threadIdx.x) * 4;
  int stride = gridDim.x * blockDim.x * 4;
  for (; i + 3 < n; i += stride) {
    float4 v = *(const float4*)(src + i);
    ushort4 o;
    o.x = f2b(v.x); o.y = f2b(v.y); o.z = f2b(v.z); o.w = f2b(v.w);
    *(ushort4*)(dst + i) = o;
  }
}

// ---------------------------------------------------------------------------
// Transpose K,V slices of QKV [16384,3072] -> KT/VT [b][1024(hd), 4096(s)]
// ---------------------------------------------------------------------------
__global__ void transpose_kv(const unsigned short* __restrict__ qkv,
                             unsigned short* __restrict__ kt,
                             unsigned short* __restrict__ vt) {
  __shared__ unsigned short tile[64][65];   // +1 pad: conflict-free
  const int st = blockIdx.x * 64;           // s tile
  const int ht = blockIdx.y * 64;           // hd tile
  const int b = blockIdx.z >> 1;
  const int which = blockIdx.z & 1;         // 0=K, 1=V
  const unsigned short* src = qkv + (size_t)(b * 4096) * 3072 + 1024 + which * 1024;
  unsigned short* dst = (which ? vt : kt) + (size_t)b * 1024 * 4096;
  const int t = threadIdx.x;
#pragma unroll
  for (int it = 0; it < 4; ++it) {
    int linear = (it * 256 + t) * 4;
    int r = linear >> 6, c = linear & 63;   // r = s idx, c = hd idx
    ushort4 v = *(const ushort4*)(src + (size_t)(st + r) * 3072 + ht + c);
    tile[r][c] = v.x; tile[r][c + 1] = v.y; tile[r][c + 2] = v.z; tile[r][c + 3] = v.w;
  }
  __syncthreads();
#pragma unroll
  for (int it = 0; it < 4; ++it) {
    int linear = (it * 256 + t) * 4;
    int r = linear >> 6, c = linear & 63;   // r = hd idx, c = s idx
    ushort4 o;
    o.x = tile[c][r]; o.y = tile[c + 1][r]; o.z = tile[c + 2][r]; o.w = tile[c + 3][r];
    *(ushort4*)(dst + (size_t)(ht + r) * 4096 + st + c) = o;
  }
}

// ---------------------------------------------------------------------------
// BT GEMM: C[M,N] = A[M,K] * B[N,K]^T  (both row-major bf16), f32 accum.
// 128x128 tile, BK=32, 4 waves (each 64x64 = 4x4 16x16 frags).
// LDS tiles [128][32] bf16, XOR-swizzled: slot' = slot ^ ((row>>1)&3)
// (write side via pre-swizzled global source; both-sides-or-neither).
// BIAS: 0=none, 1=per-row(m), 2=per-col(n). OBF16: bf16 vs f32 output.
// ---------------------------------------------------------------------------
template <int BIAS, bool OBF16>
__global__ __launch_bounds__(256, 2) void gemm_bt(
    const unsigned short* __restrict__ A, const unsigned short* __restrict__ B,
    void* __restrict__ Cout, const float* __restrict__ bias,
    int M, int N, int K, int lda, int ldb, int ldc,
    long long sA, long long sB, long long sC) {
  __shared__ unsigned short Asm_[128 * 32];
  __shared__ unsigned short Bsm_[128 * 32];
  const int tid = threadIdx.x;
  const int wave = tid >> 6, lane = tid & 63;
  const int g = lane >> 4, l15 = lane & 15;
  const int bm = blockIdx.x * 128, bn = blockIdx.y * 128;
  const unsigned short* Ab = A + (size_t)blockIdx.z * sA;
  const unsigned short* Bb = B + (size_t)blockIdx.z * sB;
  const int wm = (wave >> 1) * 64, wn = (wave & 1) * 64;

  f32x4 acc[4][4];
#pragma unroll
  for (int i = 0; i < 4; ++i)
#pragma unroll
    for (int j = 0; j < 4; ++j) acc[i][j] = (f32x4){0.f, 0.f, 0.f, 0.f};

  for (int kt = 0; kt < K; kt += 32) {
    // --- stage A,B tiles: 8KB each = 8 chunks of 1KB (64 lanes x 16B) ---
#pragma unroll
    for (int it = 0; it < 2; ++it) {
      int c = it * 4 + wave;                   // chunk 0..7
      int rr = c * 16 + (lane >> 2);           // tile row 0..127
      int sl = (lane & 3) ^ ((rr >> 1) & 3);   // pre-swizzled source slot
      gll16(Ab + (size_t)(bm + rr) * lda + kt + sl * 8, Asm_ + c * 512);
      gll16(Bb + (size_t)(bn + rr) * ldb + kt + sl * 8, Bsm_ + c * 512);
    }
    __syncthreads();   // compiler drains vmcnt before s_barrier

    bf16x8 af[4], bfr[4];
#pragma unroll
    for (int mi = 0; mi < 4; ++mi) {
      int m = wm + mi * 16 + l15;
      af[mi] = *(const bf16x8*)((const char*)Asm_ + m * 64 + ((g ^ ((m >> 1) & 3)) << 4));
    }
#pragma unroll
    for (int ni = 0; ni < 4; ++ni) {
      int n = wn + ni * 16 + l15;
      bfr[ni] = *(const bf16x8*)((const char*)Bsm_ + n * 64 + ((g ^ ((n >> 1) & 3)) << 4));
    }
#pragma unroll
    for (int mi = 0; mi < 4; ++mi)
#pragma unroll
      for (int ni = 0; ni < 4; ++ni)
        acc[mi][ni] = MFMA(af[mi], bfr[ni], acc[mi][ni]);
    __syncthreads();
  }

  // --- epilogue: C row = bm+wm+mi*16+g*4+r, col = bn+wn+ni*16+l15 ---
  if (OBF16) {
    unsigned short* C = (unsigned short*)Cout + (size_t)blockIdx.z * sC;
#pragma unroll
    for (int mi = 0; mi < 4; ++mi)
#pragma unroll
      for (int r = 0; r < 4; ++r) {
        int row = bm + wm + mi * 16 + g * 4 + r;
        float rb = (BIAS == 1) ? bias[row] : 0.f;
#pragma unroll
        for (int ni = 0; ni < 4; ++ni) {
          int col = bn + wn + ni * 16 + l15;
          float v = acc[mi][ni][r] + rb + ((BIAS == 2) ? bias[col] : 0.f);
          C[(size_t)row * ldc + col] = f2b(v);
        }
      }
  } else {
    float* C = (float*)Cout + (size_t)blockIdx.z * sC;
#pragma unroll
    for (int mi = 0; mi < 4; ++mi)
#pragma unroll
      for (int r = 0; r < 4; ++r) {
        int row = bm + wm + mi * 16 + g * 4 + r;
        float rb = (BIAS == 1) ? bias[row] : 0.f;
#pragma unroll
        for (int ni = 0; ni < 4; ++ni) {
          int col = bn + wn + ni * 16 + l15;
          C[(size_t)row * ldc + col] = acc[mi][ni][r] + rb + ((BIAS == 2) ? bias[col] : 0.f);
        }
      }
  }
}

// ---------------------------------------------------------------------------
// Fused attention per (b, h, 64-row s-tile).
// ST = Kp_h[256,64] * Q_h^T  (swapped QK^T: softmax axis mostly lane-local)
// softmax over k (=256), P -> LDS (bf16, swizzled), HO = P * Vp_h.
// Kp layout [dk, hd] (A-operand rows); Vp layout [hd, dk] (B-operand rows).
// ---------------------------------------------------------------------------
__global__ __launch_bounds__(256, 1) void attn_kernel(
    const unsigned short* __restrict__ qkv,   // [16384, 3072]
    const unsigned short* __restrict__ kp,    // [4][256][1024]
    const unsigned short* __restrict__ vp,    // [4][1024][256]
    unsigned short* __restrict__ ho) {        // [16384, 1024]
  __shared__ unsigned short Ksm[256 * 64];    // [k][d], 8 slots/row, ^ (k&7)
  __shared__ unsigned short Vsm[64 * 256];    // [d][k], 32 slots/row, ^ (d&7)
  __shared__ unsigned short Psm[64 * 256];    // [s][k], 32 slots/row, ^ (s&7)
  __shared__ float Lsm[64];

  const int tid = threadIdx.x;
  const int wave = tid >> 6, lane = tid & 63;
  const int g = lane >> 4, l15 = lane & 15;
  const int s0 = blockIdx.x * 64;
  const int h = blockIdx.y, b = blockIdx.z;

  const unsigned short* kpb = kp + (size_t)b * 256 * 1024 + h * 64;
  const unsigned short* vpb = vp + ((size_t)b * 1024 + h * 64) * 256;

  // stage Kp tile [256][64]: 32KB; chunk c: row = c*8 + lane/8, slot = lane&7
#pragma unroll
  for (int it = 0; it < 8; ++it) {
    int c = it * 4 + wave;
    int m = c * 8 + (lane >> 3);
    int sl = (lane & 7) ^ (m & 7);
    gll16(kpb + (size_t)m * 1024 + sl * 8, Ksm + c * 512);
  }
  // stage Vp tile [64][256]: 32KB; chunk c: row d = c*2 + lane/32, slot = lane&31
#pragma unroll
  for (int it = 0; it < 8; ++it) {
    int c = it * 4 + wave;
    int d = c * 2 + (lane >> 5);
    int sl = (lane & 31) ^ (d & 7);
    gll16(vpb + (size_t)d * 256 + sl * 8, Vsm + c * 512);
  }

  // Q B-fragments (held in regs): B[d, s] = Q[s = l15, d = kk*32 + 8g + i]
  const int srow = s0 + wave * 16 + l15;
  const unsigned short* qrow = qkv + (size_t)(b * 4096 + srow) * 3072 + h * 64;
  bf16x8 qf0 = *(const bf16x8*)(qrow + g * 8);
  bf16x8 qf1 = *(const bf16x8*)(qrow + 32 + g * 8);

  __syncthreads();

  // --- QK^T: ST[k=0..255][s=16 cols per wave] ---
  f32x4 st[16];
#pragma unroll
  for (int mt = 0; mt < 16; ++mt) {
    int m = (mt << 4) + l15;                  // k row
    const char* base = (const char*)Ksm + m * 128;
    bf16x8 a0 = *(const bf16x8*)(base + ((g ^ (m & 7)) << 4));
    bf16x8 a1 = *(const bf16x8*)(base + (((4 + g) ^ (m & 7)) << 4));
    f32x4 c = {0.f, 0.f, 0.f, 0.f};
    c = MFMA(a0, qf0, c);
    c = MFMA(a1, qf1, c);
    st[mt] = c;
  }

  // --- softmax over k (unnormalized; divide after PV) ---
  const float scale = 0.18033688011112042f;   // log2(e)/8
  float mx = -1e30f;
#pragma unroll
  for (int mt = 0; mt < 16; ++mt)
#pragma unroll
    for (int r = 0; r < 4; ++r) mx = fmaxf(mx, st[mt][r]);
  mx = fmaxf(mx, __shfl_xor(mx, 16));
  mx = fmaxf(mx, __shfl_xor(mx, 32));
  float sum = 0.f;
#pragma unroll
  for (int mt = 0; mt < 16; ++mt) {
    f32x4 p;
#pragma unroll
    for (int r = 0; r < 4; ++r) {
      float e = exp2f((st[mt][r] - mx) * scale);
      p[r] = e; sum += e;
    }
    st[mt] = p;
  }
  sum += __shfl_xor(sum, 16);
  sum += __shfl_xor(sum, 32);

  // write P^T rows: s = wave*16 + l15; k = mt*16 + g*4 + r (4 bf16 = 8B)
  const int sp = wave * 16 + l15;
#pragma unroll
  for (int mt = 0; mt < 16; ++mt) {
    ushort4 pb;
    pb.x = f2b(st[mt][0]); pb.y = f2b(st[mt][1]);
    pb.z = f2b(st[mt][2]); pb.w = f2b(st[mt][3]);
    int slot = 2 * mt + (g >> 1);
    *(ushort4*)((char*)Psm + sp * 512 + (((slot ^ (sp & 7)) << 4) | ((g & 1) << 3))) = pb;
  }
  if (lane < 16) Lsm[wave * 16 + lane] = sum;
  __syncthreads();

  // --- PV: C[s=16 rows per wave][d=64] ---
  f32x4 acc2[4];
#pragma unroll
  for (int i = 0; i < 4; ++i) acc2[i] = (f32x4){0.f, 0.f, 0.f, 0.f};
  const int ms = wave * 16 + l15;
#pragma unroll
  for (int ks = 0; ks < 8; ++ks) {
    bf16x8 pa = *(const bf16x8*)((const char*)Psm + ms * 512 + ((((ks << 2) + g) ^ (ms & 7)) << 4));
#pragma unroll
    for (int nf = 0; nf < 4; ++nf) {
      int n = (nf << 4) + l15;                // d col
      bf16x8 vb = *(const bf16x8*)((const char*)Vsm + n * 512 + ((((ks << 2) + g) ^ (n & 7)) << 4));
      acc2[nf] = MFMA(pa, vb, acc2[nf]);
    }
  }

  // --- normalize + store: row s = s0 + wave*16 + g*4 + r, col = h*64 + nf*16 + l15
  float rl[4];
#pragma unroll
  for (int r = 0; r < 4; ++r) rl[r] = 1.f / Lsm[wave * 16 + g * 4 + r];
#pragma unroll
  for (int nf = 0; nf < 4; ++nf)
#pragma unroll
    for (int r = 0; r < 4; ++r) {
      int srw = s0 + wave * 16 + g * 4 + r;
      ho[(size_t)(b * 4096 + srw) * 1024 + h * 64 + (nf << 4) + l15] = f2b(acc2[nf][r] * rl[r]);
    }
}

// ---------------------------------------------------------------------------
// Host orchestration
// ---------------------------------------------------------------------------
extern "C" void kernel_launch(void* const* d_in, const int* in_sizes, int n_in,
                              void* d_out, int out_size, void* d_ws, size_t ws_size,
                              hipStream_t stream) {
  (void)in_sizes; (void)n_in; (void)out_size; (void)ws_size;
  const float* x   = (const float*)d_in[0];
  const float* Wq  = (const float*)d_in[1];
  const float* Wk  = (const float*)d_in[2];
  const float* Wv  = (const float*)d_in[3];
  const float* E_w = (const float*)d_in[4];
  const float* E_b = (const float*)d_in[5];
  const float* F_w = (const float*)d_in[6];
  const float* F_b = (const float*)d_in[7];
  const float* Wo  = (const float*)d_in[8];
  const float* bo  = (const float*)d_in[9];
  float* out = (float*)d_out;

  char* ws = (char*)d_ws;
  unsigned short* xb    = (unsigned short*)(ws);              // 33,554,432 B (reused as HO)
  unsigned short* Wqkvb = (unsigned short*)(ws + 33554432);   //  6,291,456
  unsigned short* Ewb   = (unsigned short*)(ws + 39845888);   //  2,097,152
  unsigned short* Fwb   = (unsigned short*)(ws + 41943040);   //  2,097,152
  unsigned short* Wob   = (unsigned short*)(ws + 44040192);   //  2,097,152
  unsigned short* QKVb  = (unsigned short*)(ws + 46137344);   // 100,663,296
  unsigned short* KT    = (unsigned short*)(ws + 146800640);  // 33,554,432
  unsigned short* VT    = (unsigned short*)(ws + 180355072);  // 33,554,432
  unsigned short* Kp    = (unsigned short*)(ws + 213909504);  //  2,097,152
  unsigned short* Vp    = (unsigned short*)(ws + 216006656);  //  2,097,152  (total 218,103,808)
  unsigned short* HO    = xb;   // xb dead after GEMM1

  // casts
  cast_f32_bf16<<<2048, 256, 0, stream>>>(x, xb, 16777216);
  cast_f32_bf16<<<1024, 256, 0, stream>>>(Wq, Wqkvb,            1048576);
  cast_f32_bf16<<<1024, 256, 0, stream>>>(Wk, Wqkvb + 1048576,  1048576);
  cast_f32_bf16<<<1024, 256, 0, stream>>>(Wv, Wqkvb + 2097152,  1048576);
  cast_f32_bf16<<<1024, 256, 0, stream>>>(E_w, Ewb, 1048576);
  cast_f32_bf16<<<1024, 256, 0, stream>>>(F_w, Fwb, 1048576);
  cast_f32_bf16<<<1024, 256, 0, stream>>>(Wo, Wob, 1048576);

  // GEMM1: QKV = xb * Wqkvb^T   [16384,3072]
  gemm_bt<0, true><<<dim3(128, 24, 1), 256, 0, stream>>>(
      xb, Wqkvb, QKVb, nullptr, 16384, 3072, 1024, 1024, 1024, 3072, 0, 0, 0);

  // KT/VT [b][hd][s]
  transpose_kv<<<dim3(64, 16, 8), 256, 0, stream>>>(QKVb, KT, VT);

  // Kp[b][dk,hd] = E_w * KT^T + E_b(row)
  gemm_bt<1, true><<<dim3(2, 8, 4), 256, 0, stream>>>(
      Ewb, KT, Kp, E_b, 256, 1024, 4096, 4096, 4096, 1024,
      0LL, 1024LL * 4096, 256LL * 1024);

  // Vp[b][hd,dk] = VT * F_w^T + F_b(col)
  gemm_bt<2, true><<<dim3(8, 2, 4), 256, 0, stream>>>(
      VT, Fwb, Vp, F_b, 1024, 256, 4096, 4096, 4096, 256,
      1024LL * 4096, 0LL, 1024LL * 256);

  // fused attention -> HO [16384,1024]
  attn_kernel<<<dim3(64, 16, 4), 256, 0, stream>>>(QKVb, Kp, Vp, HO);

  // out = HO * Wo^T + bo   (f32)
  gemm_bt<2, false><<<dim3(128, 8, 1), 256, 0, stream>>>(
      HO, Wob, out, bo, 16384, 1024, 1024, 1024, 1024, 1024, 0, 0, 0);
}

// Round 2
// 303.536 us; speedup vs baseline: 1.4586x; 1.4586x over previous
//
#include <hip/hip_runtime.h>
#include <stdint.h>

// ---------------------------------------------------------------------------
// Types
// ---------------------------------------------------------------------------
typedef __attribute__((ext_vector_type(8))) short bf16x8;   // 8 bf16 (4 VGPRs)
typedef __attribute__((ext_vector_type(4))) float f32x4;    // MFMA accumulator

__device__ __forceinline__ unsigned short f2b(float f) {
  union { float f; uint32_t u; } v; v.f = f;
  uint32_t u = v.u;
  return (unsigned short)((u + 0x7FFFu + ((u >> 16) & 1u)) >> 16);  // RNE
}

// async global->LDS, 16B per lane. lds_uniform = wave-uniform base; HW writes
// lane i at base + i*16. Global src is per-lane.
__device__ __forceinline__ void gll16(const unsigned short* gsrc, unsigned short* lds_uniform) {
  __builtin_amdgcn_global_load_lds(
      (const __attribute__((address_space(1))) uint32_t*)gsrc,
      (__attribute__((address_space(3))) uint32_t*)lds_uniform,
      16, 0, 0);
}

#define MFMA(a, b, c) __builtin_amdgcn_mfma_f32_16x16x32_bf16((a), (b), (c), 0, 0, 0)

// ---------------------------------------------------------------------------
// Fused cast+transpose of x: read x f32 [4][4096][1024],
// write xb bf16 [16384,1024] AND xT bf16 [4][1024(c)][4096(s)].
// ---------------------------------------------------------------------------
__global__ void cast_x_dual(const float* __restrict__ x,
                            unsigned short* __restrict__ xb,
                            unsigned short* __restrict__ xT) {
  __shared__ unsigned short tile[64][65];   // +1 pad: conflict-free transpose
  const int st = blockIdx.x * 64;           // s tile
  const int ct = blockIdx.y * 64;           // c tile
  const int b = blockIdx.z;
  const int t = threadIdx.x;
#pragma unroll
  for (int it = 0; it < 4; ++it) {
    int linear = (it * 256 + t) * 4;
    int r = linear >> 6, c = linear & 63;   // r = s idx, c = c idx
    float4 v = *(const float4*)(x + ((size_t)(b * 4096 + st + r)) * 1024 + ct + c);
    ushort4 o;
    o.x = f2b(v.x); o.y = f2b(v.y); o.z = f2b(v.z); o.w = f2b(v.w);
    *(ushort4*)(xb + ((size_t)(b * 4096 + st + r)) * 1024 + ct + c) = o;
    tile[r][c] = o.x; tile[r][c + 1] = o.y; tile[r][c + 2] = o.z; tile[r][c + 3] = o.w;
  }
  __syncthreads();
#pragma unroll
  for (int it = 0; it < 4; ++it) {
    int linear = (it * 256 + t) * 4;
    int r = linear >> 6, c = linear & 63;   // r = c idx, c = s idx
    ushort4 o;
    o.x = tile[c][r]; o.y = tile[c + 1][r]; o.z = tile[c + 2][r]; o.w = tile[c + 3][r];
    *(ushort4*)(xT + ((size_t)b * 1024 + ct + r) * 4096 + st + c) = o;
  }
}

// ---------------------------------------------------------------------------
// Cast the 6 weight matrices (each exactly 1,048,576 f32) to bf16.
// blockIdx.y picks the matrix. grid.x*256*4 == 1048576.
// ---------------------------------------------------------------------------
__global__ void cast6(const float* __restrict__ s0, const float* __restrict__ s1,
                      const float* __restrict__ s2, const float* __restrict__ s3,
                      const float* __restrict__ s4, const float* __restrict__ s5,
                      unsigned short* __restrict__ d0, unsigned short* __restrict__ d1,
                      unsigned short* __restrict__ d2, unsigned short* __restrict__ d3,
                      unsigned short* __restrict__ d4, unsigned short* __restrict__ d5) {
  const float* src; unsigned short* dst;
  switch (blockIdx.y) {
    case 0: src = s0; dst = d0; break;
    case 1: src = s1; dst = d1; break;
    case 2: src = s2; dst = d2; break;
    case 3: src = s3; dst = d3; break;
    case 4: src = s4; dst = d4; break;
    default: src = s5; dst = d5; break;
  }
  int i = (blockIdx.x * 256 + threadIdx.x) * 4;
  float4 v = *(const float4*)(src + i);
  ushort4 o;
  o.x = f2b(v.x); o.y = f2b(v.y); o.z = f2b(v.z); o.w = f2b(v.w);
  *(ushort4*)(dst + i) = o;
}

// ---------------------------------------------------------------------------
// BT GEMM: C[M,N] = A[M,K] * B[N,K]^T  (both row-major bf16), f32 accum.
// 128x128 tile, BK=32, 4 waves (each 64x64 = 4x4 16x16 frags).
// LDS tiles [128][32] bf16, XOR-swizzled: slot' = slot ^ ((row>>1)&3)
// (write side via pre-swizzled global source; both-sides-or-neither).
// BIAS: 0=none, 1=per-row(m), 2=per-col(n). OBF16: bf16 vs f32 output.
// ---------------------------------------------------------------------------
template <int BIAS, bool OBF16>
__global__ __launch_bounds__(256, 2) void gemm_bt(
    const unsigned short* __restrict__ A, const unsigned short* __restrict__ B,
    void* __restrict__ Cout, const float* __restrict__ bias,
    int M, int N, int K, int lda, int ldb, int ldc,
    long long sA, long long sB, long long sC) {
  __shared__ unsigned short Asm_[128 * 32];
  __shared__ unsigned short Bsm_[128 * 32];
  const int tid = threadIdx.x;
  const int wave = tid >> 6, lane = tid & 63;
  const int g = lane >> 4, l15 = lane & 15;
  const int bm = blockIdx.x * 128, bn = blockIdx.y * 128;
  const unsigned short* Ab = A + (size_t)blockIdx.z * sA;
  const unsigned short* Bb = B + (size_t)blockIdx.z * sB;
  const int wm = (wave >> 1) * 64, wn = (wave & 1) * 64;

  f32x4 acc[4][4];
#pragma unroll
  for (int i = 0; i < 4; ++i)
#pragma unroll
    for (int j = 0; j < 4; ++j) acc[i][j] = (f32x4){0.f, 0.f, 0.f, 0.f};

  for (int kt = 0; kt < K; kt += 32) {
    // --- stage A,B tiles: 8KB each = 8 chunks of 1KB (64 lanes x 16B) ---
#pragma unroll
    for (int it = 0; it < 2; ++it) {
      int c = it * 4 + wave;                   // chunk 0..7
      int rr = c * 16 + (lane >> 2);           // tile row 0..127
      int sl = (lane & 3) ^ ((rr >> 1) & 3);   // pre-swizzled source slot
      gll16(Ab + (size_t)(bm + rr) * lda + kt + sl * 8, Asm_ + c * 512);
      gll16(Bb + (size_t)(bn + rr) * ldb + kt + sl * 8, Bsm_ + c * 512);
    }
    __syncthreads();   // compiler drains vmcnt before s_barrier

    bf16x8 af[4], bfr[4];
#pragma unroll
    for (int mi = 0; mi < 4; ++mi) {
      int m = wm + mi * 16 + l15;
      af[mi] = *(const bf16x8*)((const char*)Asm_ + m * 64 + ((g ^ ((m >> 1) & 3)) << 4));
    }
#pragma unroll
    for (int ni = 0; ni < 4; ++ni) {
      int n = wn + ni * 16 + l15;
      bfr[ni] = *(const bf16x8*)((const char*)Bsm_ + n * 64 + ((g ^ ((n >> 1) & 3)) << 4));
    }
#pragma unroll
    for (int mi = 0; mi < 4; ++mi)
#pragma unroll
      for (int ni = 0; ni < 4; ++ni)
        acc[mi][ni] = MFMA(af[mi], bfr[ni], acc[mi][ni]);
    __syncthreads();
  }

  // --- epilogue: C row = bm+wm+mi*16+g*4+r, col = bn+wn+ni*16+l15 ---
  if (OBF16) {
    unsigned short* C = (unsigned short*)Cout + (size_t)blockIdx.z * sC;
#pragma unroll
    for (int mi = 0; mi < 4; ++mi)
#pragma unroll
      for (int r = 0; r < 4; ++r) {
        int row = bm + wm + mi * 16 + g * 4 + r;
        float rb = (BIAS == 1) ? bias[row] : 0.f;
#pragma unroll
        for (int ni = 0; ni < 4; ++ni) {
          int col = bn + wn + ni * 16 + l15;
          float v = acc[mi][ni][r] + rb + ((BIAS == 2) ? bias[col] : 0.f);
          C[(size_t)row * ldc + col] = f2b(v);
        }
      }
  } else {
    float* C = (float*)Cout + (size_t)blockIdx.z * sC;
#pragma unroll
    for (int mi = 0; mi < 4; ++mi)
#pragma unroll
      for (int r = 0; r < 4; ++r) {
        int row = bm + wm + mi * 16 + g * 4 + r;
        float rb = (BIAS == 1) ? bias[row] : 0.f;
#pragma unroll
        for (int ni = 0; ni < 4; ++ni) {
          int col = bn + wn + ni * 16 + l15;
          C[(size_t)row * ldc + col] = acc[mi][ni][r] + rb + ((BIAS == 2) ? bias[col] : 0.f);
        }
      }
  }
}

// ---------------------------------------------------------------------------
// BT GEMM, 64x64 tile, BK=32, 4 waves (each 32x32 = 2x2 frags). For the
// small Kp/Vp GEMMs where 128^2 tiles would leave most CUs idle.
// ---------------------------------------------------------------------------
template <int BIAS, bool OBF16>
__global__ __launch_bounds__(256, 4) void gemm_bt64(
    const unsigned short* __restrict__ A, const unsigned short* __restrict__ B,
    void* __restrict__ Cout, const float* __restrict__ bias,
    int M, int N, int K, int lda, int ldb, int ldc,
    long long sA, long long sB, long long sC) {
  __shared__ unsigned short Asm_[64 * 32];
  __shared__ unsigned short Bsm_[64 * 32];
  const int tid = threadIdx.x;
  const int wave = tid >> 6, lane = tid & 63;
  const int g = lane >> 4, l15 = lane & 15;
  const int bm = blockIdx.x * 64, bn = blockIdx.y * 64;
  const unsigned short* Ab = A + (size_t)blockIdx.z * sA;
  const unsigned short* Bb = B + (size_t)blockIdx.z * sB;
  const int wm = (wave >> 1) * 32, wn = (wave & 1) * 32;

  f32x4 acc[2][2];
#pragma unroll
  for (int i = 0; i < 2; ++i)
#pragma unroll
    for (int j = 0; j < 2; ++j) acc[i][j] = (f32x4){0.f, 0.f, 0.f, 0.f};

  for (int kt = 0; kt < K; kt += 32) {
    // stage: 4KB per tile = 4 chunks of 1KB; wave w stages chunk w of A and B
    {
      int c = wave;
      int rr = c * 16 + (lane >> 2);           // tile row 0..63
      int sl = (lane & 3) ^ ((rr >> 1) & 3);
      gll16(Ab + (size_t)(bm + rr) * lda + kt + sl * 8, Asm_ + c * 512);
      gll16(Bb + (size_t)(bn + rr) * ldb + kt + sl * 8, Bsm_ + c * 512);
    }
    __syncthreads();

    bf16x8 af[2], bfr[2];
#pragma unroll
    for (int mi = 0; mi < 2; ++mi) {
      int m = wm + mi * 16 + l15;
      af[mi] = *(const bf16x8*)((const char*)Asm_ + m * 64 + ((g ^ ((m >> 1) & 3)) << 4));
    }
#pragma unroll
    for (int ni = 0; ni < 2; ++ni) {
      int n = wn + ni * 16 + l15;
      bfr[ni] = *(const bf16x8*)((const char*)Bsm_ + n * 64 + ((g ^ ((n >> 1) & 3)) << 4));
    }
#pragma unroll
    for (int mi = 0; mi < 2; ++mi)
#pragma unroll
      for (int ni = 0; ni < 2; ++ni)
        acc[mi][ni] = MFMA(af[mi], bfr[ni], acc[mi][ni]);
    __syncthreads();
  }

  if (OBF16) {
    unsigned short* C = (unsigned short*)Cout + (size_t)blockIdx.z * sC;
#pragma unroll
    for (int mi = 0; mi < 2; ++mi)
#pragma unroll
      for (int r = 0; r < 4; ++r) {
        int row = bm + wm + mi * 16 + g * 4 + r;
        float rb = (BIAS == 1) ? bias[row] : 0.f;
#pragma unroll
        for (int ni = 0; ni < 2; ++ni) {
          int col = bn + wn + ni * 16 + l15;
          float v = acc[mi][ni][r] + rb + ((BIAS == 2) ? bias[col] : 0.f);
          C[(size_t)row * ldc + col] = f2b(v);
        }
      }
  } else {
    float* C = (float*)Cout + (size_t)blockIdx.z * sC;
#pragma unroll
    for (int mi = 0; mi < 2; ++mi)
#pragma unroll
      for (int r = 0; r < 4; ++r) {
        int row = bm + wm + mi * 16 + g * 4 + r;
        float rb = (BIAS == 1) ? bias[row] : 0.f;
#pragma unroll
        for (int ni = 0; ni < 2; ++ni) {
          int col = bn + wn + ni * 16 + l15;
          C[(size_t)row * ldc + col] = acc[mi][ni][r] + rb + ((BIAS == 2) ? bias[col] : 0.f);
        }
      }
  }
}

// ---------------------------------------------------------------------------
// Fused attention per (b, h, 64-row s-tile).
// ST = Kp_h[256,64] * Q_h^T  (swapped QK^T: softmax axis mostly lane-local)
// softmax over k (=256), P -> LDS (bf16, swizzled), HO = P * Vp_h.
// Kp layout [dk, hd] (A-operand rows); Vp layout [hd, dk] (B-operand rows).
// ---------------------------------------------------------------------------
__global__ __launch_bounds__(256, 1) void attn_kernel(
    const unsigned short* __restrict__ q,     // [16384, 1024]
    const unsigned short* __restrict__ kp,    // [4][256][1024]
    const unsigned short* __restrict__ vp,    // [4][1024][256]
    unsigned short* __restrict__ ho) {        // [16384, 1024]
  __shared__ unsigned short Ksm[256 * 64];    // [k][d], 8 slots/row, ^ (k&7)
  __shared__ unsigned short Vsm[64 * 256];    // [d][k], 32 slots/row, ^ (d&7)
  __shared__ unsigned short Psm[64 * 256];    // [s][k], 32 slots/row, ^ (s&7)
  __shared__ float Lsm[64];

  const int tid = threadIdx.x;
  const int wave = tid >> 6, lane = tid & 63;
  const int g = lane >> 4, l15 = lane & 15;
  const int s0 = blockIdx.x * 64;
  const int h = blockIdx.y, b = blockIdx.z;

  const unsigned short* kpb = kp + (size_t)b * 256 * 1024 + h * 64;
  const unsigned short* vpb = vp + ((size_t)b * 1024 + h * 64) * 256;

  // stage Kp tile [256][64]: 32KB; chunk c: row = c*8 + lane/8, slot = lane&7
#pragma unroll
  for (int it = 0; it < 8; ++it) {
    int c = it * 4 + wave;
    int m = c * 8 + (lane >> 3);
    int sl = (lane & 7) ^ (m & 7);
    gll16(kpb + (size_t)m * 1024 + sl * 8, Ksm + c * 512);
  }
  // stage Vp tile [64][256]: 32KB; chunk c: row d = c*2 + lane/32, slot = lane&31
#pragma unroll
  for (int it = 0; it < 8; ++it) {
    int c = it * 4 + wave;
    int d = c * 2 + (lane >> 5);
    int sl = (lane & 31) ^ (d & 7);
    gll16(vpb + (size_t)d * 256 + sl * 8, Vsm + c * 512);
  }

  // Q B-fragments (held in regs): B[d, s] = Q[s = l15, d = kk*32 + 8g + i]
  const int srow = s0 + wave * 16 + l15;
  const unsigned short* qrow = q + (size_t)(b * 4096 + srow) * 1024 + h * 64;
  bf16x8 qf0 = *(const bf16x8*)(qrow + g * 8);
  bf16x8 qf1 = *(const bf16x8*)(qrow + 32 + g * 8);

  __syncthreads();

  // --- QK^T: ST[k=0..255][s=16 cols per wave] ---
  f32x4 st[16];
#pragma unroll
  for (int mt = 0; mt < 16; ++mt) {
    int m = (mt << 4) + l15;                  // k row
    const char* base = (const char*)Ksm + m * 128;
    bf16x8 a0 = *(const bf16x8*)(base + ((g ^ (m & 7)) << 4));
    bf16x8 a1 = *(const bf16x8*)(base + (((4 + g) ^ (m & 7)) << 4));
    f32x4 c = {0.f, 0.f, 0.f, 0.f};
    c = MFMA(a0, qf0, c);
    c = MFMA(a1, qf1, c);
    st[mt] = c;
  }

  // --- softmax over k (unnormalized; divide after PV) ---
  const float scale = 0.18033688011112042f;   // log2(e)/8
  float mx = -1e30f;
#pragma unroll
  for (int mt = 0; mt < 16; ++mt)
#pragma unroll
    for (int r = 0; r < 4; ++r) mx = fmaxf(mx, st[mt][r]);
  mx = fmaxf(mx, __shfl_xor(mx, 16));
  mx = fmaxf(mx, __shfl_xor(mx, 32));
  float sum = 0.f;
#pragma unroll
  for (int mt = 0; mt < 16; ++mt) {
    f32x4 p;
#pragma unroll
    for (int r = 0; r < 4; ++r) {
      float e = exp2f((st[mt][r] - mx) * scale);
      p[r] = e; sum += e;
    }
    st[mt] = p;
  }
  sum += __shfl_xor(sum, 16);
  sum += __shfl_xor(sum, 32);

  // write P^T rows: s = wave*16 + l15; k = mt*16 + g*4 + r (4 bf16 = 8B)
  const int sp = wave * 16 + l15;
#pragma unroll
  for (int mt = 0; mt < 16; ++mt) {
    ushort4 pb;
    pb.x = f2b(st[mt][0]); pb.y = f2b(st[mt][1]);
    pb.z = f2b(st[mt][2]); pb.w = f2b(st[mt][3]);
    int slot = 2 * mt + (g >> 1);
    *(ushort4*)((char*)Psm + sp * 512 + (((slot ^ (sp & 7)) << 4) | ((g & 1) << 3))) = pb;
  }
  if (lane < 16) Lsm[wave * 16 + lane] = sum;
  __syncthreads();

  // --- PV: C[s=16 rows per wave][d=64] ---
  f32x4 acc2[4];
#pragma unroll
  for (int i = 0; i < 4; ++i) acc2[i] = (f32x4){0.f, 0.f, 0.f, 0.f};
  const int ms = wave * 16 + l15;
#pragma unroll
  for (int ks = 0; ks < 8; ++ks) {
    bf16x8 pa = *(const bf16x8*)((const char*)Psm + ms * 512 + ((((ks << 2) + g) ^ (ms & 7)) << 4));
#pragma unroll
    for (int nf = 0; nf < 4; ++nf) {
      int n = (nf << 4) + l15;                // d col
      bf16x8 vb = *(const bf16x8*)((const char*)Vsm + n * 512 + ((((ks << 2) + g) ^ (n & 7)) << 4));
      acc2[nf] = MFMA(pa, vb, acc2[nf]);
    }
  }

  // --- normalize + store: row s = s0 + wave*16 + g*4 + r, col = h*64 + nf*16 + l15
  float rl[4];
#pragma unroll
  for (int r = 0; r < 4; ++r) rl[r] = 1.f / Lsm[wave * 16 + g * 4 + r];
#pragma unroll
  for (int nf = 0; nf < 4; ++nf)
#pragma unroll
    for (int r = 0; r < 4; ++r) {
      int srw = s0 + wave * 16 + g * 4 + r;
      ho[(size_t)(b * 4096 + srw) * 1024 + h * 64 + (nf << 4) + l15] = f2b(acc2[nf][r] * rl[r]);
    }
}

// ---------------------------------------------------------------------------
// Host orchestration
// ---------------------------------------------------------------------------
extern "C" void kernel_launch(void* const* d_in, const int* in_sizes, int n_in,
                              void* d_out, int out_size, void* d_ws, size_t ws_size,
                              hipStream_t stream) {
  (void)in_sizes; (void)n_in; (void)out_size; (void)ws_size;
  const float* x   = (const float*)d_in[0];
  const float* Wq  = (const float*)d_in[1];
  const float* Wk  = (const float*)d_in[2];
  const float* Wv  = (const float*)d_in[3];
  const float* E_w = (const float*)d_in[4];
  const float* E_b = (const float*)d_in[5];
  const float* F_w = (const float*)d_in[6];
  const float* F_b = (const float*)d_in[7];
  const float* Wo  = (const float*)d_in[8];
  const float* bo  = (const float*)d_in[9];
  float* out = (float*)d_out;

  char* ws = (char*)d_ws;
  unsigned short* xb   = (unsigned short*)(ws);               // 33,554,432 (reused as HO)
  unsigned short* xT   = (unsigned short*)(ws + 33554432);    // 33,554,432  [4][1024][4096]
  unsigned short* Qb   = (unsigned short*)(ws + 67108864);    // 33,554,432  [16384][1024]
  unsigned short* Wqb  = (unsigned short*)(ws + 100663296);   //  2,097,152
  unsigned short* Wkb  = (unsigned short*)(ws + 102760448);   //  2,097,152
  unsigned short* Wvb  = (unsigned short*)(ws + 104857600);   //  2,097,152
  unsigned short* Wob  = (unsigned short*)(ws + 106954752);   //  2,097,152
  unsigned short* EFb  = (unsigned short*)(ws + 109051904);   //  4,194,304  [512][4096]
  unsigned short* xEF  = (unsigned short*)(ws + 113246208);   //  4,194,304  [4][512][1024]
  unsigned short* Kp   = (unsigned short*)(ws + 117440512);   //  2,097,152  [4][256][1024]
  unsigned short* Vp   = (unsigned short*)(ws + 119537664);   //  2,097,152  [4][1024][256]
  float*          EFbias = (float*)(ws + 121634816);          //  2,048      [512]
  unsigned short* HO   = xb;   // xb dead after Q-GEMM

  // concat E_b,F_b -> EFbias[512]
  hipMemcpyAsync(EFbias, E_b, 256 * sizeof(float), hipMemcpyDeviceToDevice, stream);
  hipMemcpyAsync(EFbias + 256, F_b, 256 * sizeof(float), hipMemcpyDeviceToDevice, stream);

  // x -> xb (row-major bf16) + xT (transposed bf16)
  cast_x_dual<<<dim3(64, 16, 4), 256, 0, stream>>>(x, xb, xT);
  // weights -> bf16 (E_w,F_w land adjacent in EFb => [E;F] concat [512,4096])
  cast6<<<dim3(1024, 6), 256, 0, stream>>>(
      Wq, Wk, Wv, E_w, F_w, Wo,
      Wqb, Wkb, Wvb, EFb, EFb + 2097152 / 2, Wob);

  // Q = xb * Wq^T   [16384,1024]
  gemm_bt<0, true><<<dim3(128, 8, 1), 256, 0, stream>>>(
      xb, Wqb, Qb, nullptr, 16384, 1024, 1024, 1024, 1024, 1024, 0, 0, 0);

  // xEF[b] = [E;F] * xT[b]^T + EFbias(row)   [4][512,1024]
  gemm_bt<1, true><<<dim3(4, 8, 4), 256, 0, stream>>>(
      EFb, xT, xEF, EFbias, 512, 1024, 4096, 4096, 4096, 1024,
      0LL, 1024LL * 4096, 512LL * 1024);

  // Kp[b][dk,hd] = xE[b] * Wk^T   (xE = rows 0..255 of xEF[b])
  gemm_bt64<0, true><<<dim3(4, 16, 4), 256, 0, stream>>>(
      xEF, Wkb, Kp, nullptr, 256, 1024, 1024, 1024, 1024, 1024,
      512LL * 1024, 0LL, 256LL * 1024);

  // Vp[b][hd,dk] = Wv * xF[b]^T   (xF = rows 256..511 of xEF[b])
  gemm_bt64<0, true><<<dim3(16, 4, 4), 256, 0, stream>>>(
      Wvb, xEF + 256 * 1024, Vp, nullptr, 1024, 256, 1024, 1024, 1024, 256,
      0LL, 512LL * 1024, 1024LL * 256);

  // fused attention -> HO [16384,1024]
  attn_kernel<<<dim3(64, 16, 4), 256, 0, stream>>>(Qb, Kp, Vp, HO);

  // out = HO * Wo^T + bo   (f32)
  gemm_bt<2, false><<<dim3(128, 8, 1), 256, 0, stream>>>(
      HO, Wob, out, bo, 16384, 1024, 1024, 1024, 1024, 1024, 0, 0, 0);
}